// Round 12
// baseline (451.336 us; speedup 1.0000x reference)
//
#include <hip/hip_runtime.h>
#include <hip/hip_bf16.h>

// ---------------------------------------------------------------------------
// PCELayer R17: fixes R16's workspace-aliasing race. R16 fused combine+pw1
// but h1cl (64MB at YS_OFF) overlapped ys[e=0..3], which other concurrent
// blocks still read -> absmax 0.859. Fix: conditional layout.
//  Layout A (ws_size >= 220.7MB): h1cl at YS_OFF+134.2MB (disjoint); fused
//    combine_pw1 runs; h2cl/h3 recycle the dead ys region.
//  Layout B (fallback): R15-verified path (combine_cl -> ccl -> pw1_mfma),
//    original safe aliasing (pw1 reads ccl, not ys).
// conv_mfma: single 2048-block dispatch (R10 pareto kernel).
// Everything else as R15 (rcp-SiLU, pw2 grid 512, prep merged, no memset).
// ---------------------------------------------------------------------------

#define B_ 16
#define CIN_ 128
#define COUT_ 128
#define H_ 64
#define W_ 64
#define HW_ 4096
#define E_ 8
#define FF_ 8
#define GC_ 32
#define HID_ 64
#define HC_ 512

typedef __hip_bfloat16 bf16;
typedef __bf16 bf16x8 __attribute__((ext_vector_type(8)));
typedef float f32x4 __attribute__((ext_vector_type(4)));
typedef float f32x16 __attribute__((ext_vector_type(16)));

__device__ __forceinline__ float siluf(float v) {
  return v * __builtin_amdgcn_rcpf(1.f + __expf(-v));
}
__device__ __forceinline__ float bf2f(bf16 v) { return __bfloat162float(v); }
__device__ __forceinline__ bf16 f2bf(float v) { return __float2bfloat16(v); }

__device__ __forceinline__ void async16(void* lds, const void* g) {
  __builtin_amdgcn_global_load_lds(
      (const __attribute__((address_space(1))) unsigned int*)g,
      (__attribute__((address_space(3))) unsigned int*)lds, 16, 0, 0);
}

// ---------------- merged prep: xt | wt | wpT | gate+statszero ---------------
__global__ __launch_bounds__(256) void prep_kernel(
    const float* __restrict__ x, bf16* __restrict__ xT,
    const float* __restrict__ w_exp, bf16* __restrict__ wT,
    const float* __restrict__ w_pw1, const float* __restrict__ w_pw2,
    bf16* __restrict__ wp1T, bf16* __restrict__ wp2T,
    const float* __restrict__ w1, const float* __restrict__ b1,
    const float* __restrict__ w2, const float* __restrict__ b2,
    float* __restrict__ wts) {
  __shared__ float t[128][65];
  int blk = blockIdx.x;
  int tid = threadIdx.x;

  if (blk < 1024) {
    int b = blk >> 6, h = blk & 63;
    int w = tid & 63, c4 = tid >> 6;
    const float* xb = x + ((size_t)(b * 128) * 64 + h) * 64;
#pragma unroll 4
    for (int rep = 0; rep < 32; ++rep) {
      int ci = rep * 4 + c4;
      t[ci][w] = xb[(size_t)ci * HW_ + w];
    }
    __syncthreads();
    bf16* dst = xT + (size_t)(b * 64 + h) * 8192;
#pragma unroll 4
    for (int rep = 0; rep < 32; ++rep) {
      int o = rep * 256 + tid;
      int cg = o >> 9, w2 = (o >> 3) & 63, lo = o & 7;
      dst[o] = f2bf(t[cg * 8 + lo][w2]);
    }
  } else if (blk < 5632) {
    int idx = (blk - 1024) * 256 + tid;
    if (idx < 1179648) {
      int lo = idx & 7;
      int co = (idx >> 3) & 127;
      int cg = (idx >> 10) & 15;
      int rest = idx >> 14;
      int tap = rest % 9, e = rest / 9;
      int ci = cg * 8 + lo;
      wT[idx] = f2bf(w_exp[(((size_t)(e * 128 + co) * 128 + ci) * 9) + tap]);
    }
  } else if (blk < 6144) {
    int idx = (blk - 5632) * 256 + tid;
    if (idx < 65536) wp1T[idx] = f2bf(w_pw1[idx]);
    else wp2T[idx - 65536] = f2bf(w_pw2[idx - 65536]);
  } else {
    uint4* z = (uint4*)((char*)wts + 1024);
    for (int i = tid; i < 960; i += 256) z[i] = make_uint4(0u, 0u, 0u, 0u);
    int p = tid;
    if (p >= 16) return;
    int i = p >> 2, j = p & 3;
    float cy = (i + 0.5f) * 0.25f;
    float cx = (j + 0.5f) * 0.25f;
    float feats[GC_];
#pragma unroll
    for (int f = 0; f < FF_; ++f) {
      float fr = 3.14159265358979f * (float)(1 << f);
      float ay = cy * fr, ax = cx * fr;
      feats[f] = sinf(ay);
      feats[FF_ + f] = cosf(ay);
      feats[2 * FF_ + f] = sinf(ax);
      feats[3 * FF_ + f] = cosf(ax);
    }
    float hid[HID_];
    for (int k = 0; k < HID_; ++k) {
      float a = b1[k];
#pragma unroll
      for (int m = 0; m < GC_; ++m) a = fmaf(feats[m], w1[m * HID_ + k], a);
      hid[k] = siluf(a);
    }
    float lg[E_];
    float mx = -1e30f;
#pragma unroll
    for (int e = 0; e < E_; ++e) {
      float a = b2[e];
      for (int k = 0; k < HID_; ++k) a = fmaf(hid[k], w2[k * E_ + e], a);
      lg[e] = a;
      mx = fmaxf(mx, a);
    }
    float s = 0.f;
#pragma unroll
    for (int e = 0; e < E_; ++e) { lg[e] = __expf(lg[e] - mx); s += lg[e]; }
    float inv = 1.f / s;
#pragma unroll
    for (int e = 0; e < E_; ++e) wts[p * E_ + e] = lg[e] * inv;
  }
}

// ---------------- expert conv via MFMA (R10 v7: 12-step SW pipeline) -------
__global__ __launch_bounds__(256, 2) void conv_mfma(
    const bf16* __restrict__ xT, const bf16* __restrict__ wT,
    float* __restrict__ statsE, bf16* __restrict__ ys) {
  __shared__ __align__(16) char xls[4 * 6336];
  __shared__ __align__(16) char wls[2][3 * 8192];
  __shared__ float red[4][8][2];

  int blk = blockIdx.x;
  int xcd = blk & 7;
  int r2 = blk >> 3;
  int b = xcd * 2 + (r2 & 1);
  int rest = r2 >> 1;
  int rt = rest & 15, e = rest >> 4;

  int tid = threadIdx.x, lane = tid & 63, wave = tid >> 6;
  int hi = lane >> 5, l31 = lane & 31;
  int h0 = rt * 4;

  if (tid < 48) {
    int cg = tid / 12, rem = tid % 12;
    int r = rem >> 1, edge = rem & 1;
    *(uint4*)(xls + cg * 6336 + r * 1056 + edge * 1040) = make_uint4(0u, 0u, 0u, 0u);
  }
  int rbad = (rt == 0) ? 0 : (rt == 15 ? 5 : -1);
  if (rbad >= 0) {
    int cg = tid >> 6, slot = (tid & 63) + 1;
    *(uint4*)(xls + cg * 6336 + rbad * 1056 + slot * 16) = make_uint4(0u, 0u, 0u, 0u);
  }

  f32x16 acc[4][2];
#pragma unroll
  for (int mt = 0; mt < 4; ++mt)
#pragma unroll
    for (int nt = 0; nt < 2; ++nt)
#pragma unroll
      for (int r = 0; r < 16; ++r) acc[mt][nt][r] = 0.f;

  for (int q = 0; q < 4; ++q) {
    if (q) __syncthreads();
    {
      int cg = wave;
#pragma unroll
      for (int r = 0; r < 6; ++r) {
        int h = h0 - 1 + r;
        if ((unsigned)h < 64u) {
          const char* g = (const char*)xT +
              ((size_t)((b * 64 + h) * 16) + q * 4 + cg) * 1024 + lane * 16;
          async16(xls + cg * 6336 + r * 1056 + 16, g);
        }
      }
    }
#pragma unroll
    for (int s = 0; s < 6; ++s) {
      int seg = wave * 6 + s;
      int tap = seg >> 3, rem = seg & 7;
      int cg = rem >> 1, cb = rem & 1;
      const char* g = (const char*)wT +
          ((size_t)(((e * 9 + tap) * 16) + q * 4 + cg) * 128 + cb * 64) * 16 + lane * 16;
      async16(wls[0] + (tap * 4 + cg) * 2048 + cb * 1024, g);
    }
    __syncthreads();

    for (int dr = 0; dr < 3; ++dr) {
      int buf = dr & 1;
      if (dr < 2) {
#pragma unroll
        for (int s = 0; s < 6; ++s) {
          int seg = wave * 6 + s;
          int tap = seg >> 3, rem = seg & 7;
          int cg = rem >> 1, cb = rem & 1;
          const char* g = (const char*)wT +
              ((size_t)(((e * 9 + (dr + 1) * 3 + tap) * 16) + q * 4 + cg) * 128 + cb * 64) * 16 +
              lane * 16;
          async16(wls[buf ^ 1] + (tap * 4 + cg) * 2048 + cb * 1024, g);
        }
      }
      int r_local = wave + dr;
      const char* wb = wls[buf];
      const char* xrow = xls;
      bf16x8 afp[2][2], bfp[2][2];
      {
        int cgl = hi;
        afp[0][0] = *(const bf16x8*)(wb + cgl * 2048 + (0 * 32 + l31) * 16);
        afp[0][1] = *(const bf16x8*)(wb + cgl * 2048 + (1 * 32 + l31) * 16);
        const char* xr = xrow + cgl * 6336 + r_local * 1056;
        bfp[0][0] = *(const bf16x8*)(xr + (0 * 32 + l31 + 0) * 16);
        bfp[0][1] = *(const bf16x8*)(xr + (1 * 32 + l31 + 0) * 16);
      }
#pragma unroll
      for (int s = 0; s < 12; ++s) {
        int mh = s & 1;
        int cura = s & 1, curb = (s >> 1) & 1;
        if (s < 11) {
          int s1 = s + 1;
          int ds1 = s1 >> 2, ks1 = (s1 >> 1) & 1, mh1 = s1 & 1;
          int cgl1 = ks1 * 2 + hi;
          const char* wt1 = wb + ds1 * 8192 + cgl1 * 2048;
          afp[s1 & 1][0] = *(const bf16x8*)(wt1 + ((mh1 * 2 + 0) * 32 + l31) * 16);
          afp[s1 & 1][1] = *(const bf16x8*)(wt1 + ((mh1 * 2 + 1) * 32 + l31) * 16);
          if (mh1 == 0) {
            const char* xr1 = xrow + cgl1 * 6336 + r_local * 1056;
            bfp[(s1 >> 1) & 1][0] = *(const bf16x8*)(xr1 + (0 * 32 + l31 + ds1) * 16);
            bfp[(s1 >> 1) & 1][1] = *(const bf16x8*)(xr1 + (1 * 32 + l31 + ds1) * 16);
          }
        }
#pragma unroll
        for (int i = 0; i < 2; ++i)
#pragma unroll
          for (int nt = 0; nt < 2; ++nt)
            acc[mh * 2 + i][nt] = __builtin_amdgcn_mfma_f32_32x32x16_bf16(
                afp[cura][i], bfp[curb][nt], acc[mh * 2 + i][nt], 0, 0, 0);
      }
      if (dr < 2) __syncthreads();
    }
  }

  int hh = h0 + wave;
  bf16* yb = ys + (size_t)((e * 16 + b) * 128) * 4096;
#pragma unroll
  for (int mt = 0; mt < 4; ++mt) {
    float s0 = 0.f, ss0 = 0.f, s1 = 0.f, ss1 = 0.f;
#pragma unroll
    for (int nt = 0; nt < 2; ++nt) {
      int w = nt * 32 + l31;
      int pos = hh * 64 + w;
#pragma unroll
      for (int r = 0; r < 16; ++r) {
        float v = acc[mt][nt][r];
        if (r < 8) { s0 += v; ss0 += v * v; } else { s1 += v; ss1 += v * v; }
        int row = (r & 3) + 8 * (r >> 2) + 4 * hi;
        yb[(size_t)(mt * 32 + row) * 4096 + pos] = f2bf(v);
      }
    }
#pragma unroll
    for (int off = 32; off; off >>= 1) {
      s0 += __shfl_down(s0, off, 64);
      ss0 += __shfl_down(ss0, off, 64);
      s1 += __shfl_down(s1, off, 64);
      ss1 += __shfl_down(ss1, off, 64);
    }
    if (lane == 0) {
      red[wave][mt * 2][0] = s0; red[wave][mt * 2][1] = ss0;
      red[wave][mt * 2 + 1][0] = s1; red[wave][mt * 2 + 1][1] = ss1;
    }
  }
  __syncthreads();
  if (tid < 16) {
    int g = tid >> 1, which = tid & 1;
    float t = red[0][g][which] + red[1][g][which] + red[2][g][which] + red[3][g][which];
    atomicAdd(&statsE[((e * 16 + b) * 8 + g) * 2 + which], t);
  }
}

// ---------------- combine+pw1 fused (layout A: h1cl disjoint from ys) ------
__global__ __launch_bounds__(256) void combine_pw1(
    const float* __restrict__ x, const bf16* __restrict__ ys,
    const float* __restrict__ stE, const float* __restrict__ gns,
    const float* __restrict__ gnb, const float* __restrict__ wts,
    const bf16* __restrict__ wp1T, bf16* __restrict__ h1cl,
    float* __restrict__ stats1) {
  __shared__ __align__(16) char bls[32768];
  __shared__ __align__(16) char ls2[34816];
  __shared__ float red[4][2][2];

  int blk = blockIdx.x;
  int xcd = blk & 7;
  int rest = blk >> 3;
  int b = xcd * 2 + (rest & 1);
  int hpair = rest >> 1;
  int h0 = hpair * 2;
  int n0 = b * 4096 + h0 * 64;

  int t = threadIdx.x, lane = t & 63, wave = t >> 6;
  int quad = lane >> 4, l15 = lane & 15;

  {
    int oct = t & 7, cq = t >> 3;
    int w0 = oct * 8;
    int gidx = cq >> 2;
    int pid = (h0 >> 4) * 4 + (w0 >> 4);

    float m_[8], r_[8], wt_[8];
#pragma unroll
    for (int e = 0; e < 8; ++e) {
      float S = stE[((e * 16 + b) * 8 + gidx) * 2];
      float SS = stE[((e * 16 + b) * 8 + gidx) * 2 + 1];
      float mean = S * (1.f / 65536.f);
      float var = SS * (1.f / 65536.f) - mean * mean;
      m_[e] = mean;
      r_[e] = rsqrtf(var + 1e-5f);
      wt_[e] = wts[pid * 8 + e];
    }

#pragma unroll
    for (int hh = 0; hh < 2; ++hh) {
      int pos = (h0 + hh) * 64 + w0;
#pragma unroll
      for (int k = 0; k < 4; ++k) {
        int co = cq * 4 + k;
        const float* xp = x + ((size_t)(b * 128 + co) << 12) + pos;
        float v[8];
        float4 xa = *(const float4*)xp;
        float4 xb2 = *(const float4*)(xp + 4);
        v[0] = xa.x; v[1] = xa.y; v[2] = xa.z; v[3] = xa.w;
        v[4] = xb2.x; v[5] = xb2.y; v[6] = xb2.z; v[7] = xb2.w;
#pragma unroll
        for (int e = 0; e < 8; ++e) {
          uint4 u = *(const uint4*)(ys + ((size_t)((e * 16 + b) * 128 + co) << 12) + pos);
          const bf16* pv = (const bf16*)&u;
          float sc = r_[e] * gns[e * 128 + co];
          float sh = gnb[e * 128 + co] - m_[e] * sc;
#pragma unroll
          for (int j = 0; j < 8; ++j) {
            float yn = bf2f(pv[j]) * sc + sh;
            v[j] = fmaf(siluf(yn), wt_[e], v[j]);
          }
        }
        bf16* bb = (bf16*)bls + (co >> 3) * 1024 + (hh * 64 + w0) * 8 + (co & 7);
#pragma unroll
        for (int j = 0; j < 8; ++j) bb[j * 8] = f2bf(v[j]);
      }
    }
  }

  for (int mtile = 0; mtile < 4; ++mtile) {
    int m0 = mtile * 128;
    char* als = ls2;
#pragma unroll
    for (int i = 0; i < 8; ++i) {
      int id = t + 256 * i;
      int r = id >> 4, c = id & 15;
      *(uint4*)(als + c * 2048 + r * 16) =
          *(const uint4*)((const char*)wp1T + (size_t)(m0 + r) * 256 + c * 16);
    }
    __syncthreads();  // als (+bls combine writes on iter 0) visible

    f32x4 acc[8][2];
#pragma unroll
    for (int mt = 0; mt < 8; ++mt)
#pragma unroll
      for (int nt = 0; nt < 2; ++nt) acc[mt][nt] = (f32x4){0.f, 0.f, 0.f, 0.f};

#pragma unroll
    for (int kc = 0; kc < 4; ++kc) {
      int cgq = kc * 4 + quad;
      bf16x8 af[8];
#pragma unroll
      for (int mt = 0; mt < 8; ++mt)
        af[mt] = *(const bf16x8*)(als + cgq * 2048 + (mt * 16 + l15) * 16);
      bf16x8 bfr[2];
#pragma unroll
      for (int nt = 0; nt < 2; ++nt)
        bfr[nt] = *(const bf16x8*)(bls + cgq * 2048 + (wave * 32 + nt * 16 + l15) * 16);
#pragma unroll
      for (int mt = 0; mt < 8; ++mt)
#pragma unroll
        for (int nt = 0; nt < 2; ++nt)
          acc[mt][nt] = __builtin_amdgcn_mfma_f32_16x16x32_bf16(
              af[mt], bfr[nt], acc[mt][nt], 0, 0, 0);
    }

    __syncthreads();
    float s[2] = {0.f, 0.f}, ss[2] = {0.f, 0.f};
    bf16* tile = (bf16*)ls2;
#pragma unroll
    for (int mt = 0; mt < 8; ++mt) {
      int gi = mt >> 2;
#pragma unroll
      for (int nt = 0; nt < 2; ++nt) {
        int n = wave * 32 + nt * 16 + l15;
#pragma unroll
        for (int r = 0; r < 4; ++r) {
          float v = acc[mt][nt][r];
          s[gi] += v;
          ss[gi] += v * v;
          tile[n * 132 + mt * 16 + quad * 4 + r] = f2bf(v);
        }
      }
    }
#pragma unroll
    for (int gi = 0; gi < 2; ++gi) {
#pragma unroll
      for (int off = 32; off; off >>= 1) {
        s[gi] += __shfl_down(s[gi], off, 64);
        ss[gi] += __shfl_down(ss[gi], off, 64);
      }
    }
    if (lane == 0) {
      red[wave][0][0] = s[0]; red[wave][0][1] = ss[0];
      red[wave][1][0] = s[1]; red[wave][1][1] = ss[1];
    }
    __syncthreads();
    if (t < 4) {
      int gi = t >> 1, which = t & 1;
      float v = red[0][gi][which] + red[1][gi][which] + red[2][gi][which] + red[3][gi][which];
      atomicAdd(&stats1[(b * 8 + mtile * 2 + gi) * 2 + which], v);
    }
#pragma unroll
    for (int i = 0; i < 8; ++i) {
      int id = t + 256 * i;
      int r = id >> 4, q = id & 15;
      char* dst = (char*)h1cl + (size_t)(n0 + r) * 1024 + m0 * 2 + q * 16;
      const char* src = (const char*)tile + r * 264 + q * 16;
      *(uint4*)dst = *(const uint4*)src;
    }
    __syncthreads();
  }
}

// ---------------- combine -> bf16 channels-last (fallback, R15) ------------
__global__ __launch_bounds__(256) void combine_cl(
    const float* __restrict__ x, const bf16* __restrict__ ys,
    const float* __restrict__ stE, const float* __restrict__ gns,
    const float* __restrict__ gnb, const float* __restrict__ wts,
    bf16* __restrict__ ccl) {
  __shared__ bf16 tile[64][132];
  int blk = blockIdx.x;
  int xcd = blk & 7;
  int k2 = blk >> 3;
  int b = xcd * 2 + (k2 >> 6);
  int h = k2 & 63;
  int t = threadIdx.x;
  int oct = t & 7, cq = t >> 3;
  int w0 = oct * 8;
  int gidx = cq >> 2;
  int pid = (h >> 4) * 4 + (w0 >> 4);
  int pos = h * 64 + w0;

  float m_[8], r_[8], wt_[8];
#pragma unroll
  for (int e = 0; e < 8; ++e) {
    float S = stE[((e * 16 + b) * 8 + gidx) * 2];
    float SS = stE[((e * 16 + b) * 8 + gidx) * 2 + 1];
    float mean = S * (1.f / 65536.f);
    float var = SS * (1.f / 65536.f) - mean * mean;
    m_[e] = mean;
    r_[e] = rsqrtf(var + 1e-5f);
    wt_[e] = wts[pid * 8 + e];
  }

#pragma unroll
  for (int k = 0; k < 4; ++k) {
    int co = cq * 4 + k;
    const float* xp = x + ((size_t)(b * 128 + co) << 12) + pos;
    float v[8];
    float4 xa = *(const float4*)xp;
    float4 xb2 = *(const float4*)(xp + 4);
    v[0] = xa.x; v[1] = xa.y; v[2] = xa.z; v[3] = xa.w;
    v[4] = xb2.x; v[5] = xb2.y; v[6] = xb2.z; v[7] = xb2.w;
#pragma unroll
    for (int e = 0; e < 8; ++e) {
      uint4 u = *(const uint4*)(ys + ((size_t)((e * 16 + b) * 128 + co) << 12) + pos);
      const bf16* pv = (const bf16*)&u;
      float sc = r_[e] * gns[e * 128 + co];
      float sh = gnb[e * 128 + co] - m_[e] * sc;
#pragma unroll
      for (int j = 0; j < 8; ++j) {
        float yn = bf2f(pv[j]) * sc + sh;
        v[j] = fmaf(siluf(yn), wt_[e], v[j]);
      }
    }
#pragma unroll
    for (int j = 0; j < 8; ++j) tile[w0 + j][co] = f2bf(v[j]);
  }
  __syncthreads();
  int row = t >> 2, q = t & 3;
  char* dst = (char*)ccl + ((size_t)(b * 4096 + h * 64 + row)) * 256 + q * 64;
  const char* src = (const char*)&tile[row][0] + q * 64;
#pragma unroll
  for (int i = 0; i < 4; ++i)
    *(uint4*)(dst + i * 16) = *(const uint4*)(src + i * 16);
}

// ---------------- pw1 MFMA (fallback, R15: B staged once, mtile loop) ------
__global__ __launch_bounds__(256) void pw1_mfma(
    const bf16* __restrict__ ccl, const bf16* __restrict__ wp1T,
    bf16* __restrict__ h1cl, float* __restrict__ stats1) {
  __shared__ __align__(16) char bls[32768];
  __shared__ __align__(16) char ls2[34816];
  __shared__ float red[4][2][2];
  int blk = blockIdx.x;
  int n0 = blk * 128;
  int t = threadIdx.x, lane = t & 63, wave = t >> 6;
  int quad = lane >> 4, l15 = lane & 15;
  int b = n0 >> 12;

#pragma unroll
  for (int i = 0; i < 8; ++i) {
    int id = t + 256 * i;
    int r = id >> 4, c = id & 15;
    *(uint4*)(bls + c * 2048 + r * 16) =
        *(const uint4*)((const char*)ccl + (size_t)(n0 + r) * 256 + c * 16);
  }

  for (int mtile = 0; mtile < 4; ++mtile) {
    int m0 = mtile * 128;
    char* als = ls2;
#pragma unroll
    for (int i = 0; i < 8; ++i) {
      int id = t + 256 * i;
      int r = id >> 4, c = id & 15;
      *(uint4*)(als + c * 2048 + r * 16) =
          *(const uint4*)((const char*)wp1T + (size_t)(m0 + r) * 256 + c * 16);
    }
    __syncthreads();

    f32x4 acc[8][2];
#pragma unroll
    for (int mt = 0; mt < 8; ++mt)
#pragma unroll
      for (int nt = 0; nt < 2; ++nt) acc[mt][nt] = (f32x4){0.f, 0.f, 0.f, 0.f};

#pragma unroll
    for (int kc = 0; kc < 4; ++kc) {
      int cgq = kc * 4 + quad;
      bf16x8 af[8];
#pragma unroll
      for (int mt = 0; mt < 8; ++mt)
        af[mt] = *(const bf16x8*)(als + cgq * 2048 + (mt * 16 + l15) * 16);
      bf16x8 bfr[2];
#pragma unroll
      for (int nt = 0; nt < 2; ++nt)
        bfr[nt] = *(const bf16x8*)(bls + cgq * 2048 + (wave * 32 + nt * 16 + l15) * 16);
#pragma unroll
      for (int mt = 0; mt < 8; ++mt)
#pragma unroll
        for (int nt = 0; nt < 2; ++nt)
          acc[mt][nt] = __builtin_amdgcn_mfma_f32_16x16x32_bf16(
              af[mt], bfr[nt], acc[mt][nt], 0, 0, 0);
    }

    __syncthreads();
    float s[2] = {0.f, 0.f}, ss[2] = {0.f, 0.f};
    bf16* tile = (bf16*)ls2;
#pragma unroll
    for (int mt = 0; mt < 8; ++mt) {
      int gi = mt >> 2;
#pragma unroll
      for (int nt = 0; nt < 2; ++nt) {
        int n = wave * 32 + nt * 16 + l15;
#pragma unroll
        for (int r = 0; r < 4; ++r) {
          float v = acc[mt][nt][r];
          s[gi] += v;
          ss[gi] += v * v;
          tile[n * 132 + mt * 16 + quad * 4 + r] = f2bf(v);
        }
      }
    }
#pragma unroll
    for (int gi = 0; gi < 2; ++gi) {
#pragma unroll
      for (int off = 32; off; off >>= 1) {
        s[gi] += __shfl_down(s[gi], off, 64);
        ss[gi] += __shfl_down(ss[gi], off, 64);
      }
    }
    if (lane == 0) {
      red[wave][0][0] = s[0]; red[wave][0][1] = ss[0];
      red[wave][1][0] = s[1]; red[wave][1][1] = ss[1];
    }
    __syncthreads();
    if (t < 4) {
      int gi = t >> 1, which = t & 1;
      float v = red[0][gi][which] + red[1][gi][which] + red[2][gi][which] + red[3][gi][which];
      atomicAdd(&stats1[(b * 8 + mtile * 2 + gi) * 2 + which], v);
    }
#pragma unroll
    for (int i = 0; i < 8; ++i) {
      int id = t + 256 * i;
      int r = id >> 4, q = id & 15;
      char* dst = (char*)h1cl + (size_t)(n0 + r) * 1024 + m0 * 2 + q * 16;
      const char* src = (const char*)tile + r * 264 + q * 16;
      *(uint4*)dst = *(const uint4*)src;
    }
    __syncthreads();
  }
}

// ---------------- dw3x3: LDS-staged GN1+SiLU tile + sliding stencil --------
__global__ __launch_bounds__(256) void dw_cl(
    const bf16* __restrict__ h1cl, const float* __restrict__ w_dw,
    const float* __restrict__ st1, const float* __restrict__ gs,
    const float* __restrict__ gb, bf16* __restrict__ h2cl,
    float* __restrict__ stats2) {
  __shared__ __align__(16) bf16 tile[18 * 66 * 16];
  __shared__ float red2[4][2];
  int blk = blockIdx.x;
  int ht = blk & 3, hcg = (blk >> 2) & 31, b = blk >> 7;
  int h0 = ht * 16;
  int hc0 = hcg * 16;
  int hcb = hcg >> 2;
  int t = threadIdx.x;

  float S1 = st1[(b * 8 + hcb) * 2], SS1 = st1[(b * 8 + hcb) * 2 + 1];
  float mean = S1 * (1.f / 262144.f);
  float var1 = SS1 * (1.f / 262144.f) - mean * mean;
  float rstd = rsqrtf(var1 + 1e-5f);
  float scale[16], shift[16];
#pragma unroll
  for (int j = 0; j < 16; ++j) {
    float g = gs[hc0 + j];
    scale[j] = rstd * g;
    shift[j] = gb[hc0 + j] - mean * rstd * g;
  }

  for (int i = 0; i < 5; ++i) {
    int idx = t + 256 * i;
    if (idx >= 1188) break;
    int row = idx / 66, wslot = idx - row * 66;
    int hh = h0 - 1 + row;
    int w = wslot - 1;
    int swz = (wslot >> 2) & 3;
    bf16* dst = tile + (row * 66 + wslot) * 16;
    if ((unsigned)hh < 64u && (unsigned)w < 64u) {
      const char* p = (const char*)h1cl + ((size_t)(b * 4096 + hh * 64 + w) * 512 + hc0) * 2;
      uint4 a0 = *(const uint4*)p;
      uint4 a1 = *(const uint4*)(p + 16);
      const bf16* pv = (const bf16*)&a0;
      const bf16* pv1 = (const bf16*)&a1;
      bf16 outv[16];
#pragma unroll
      for (int j = 0; j < 8; ++j)
        outv[j] = f2bf(siluf(bf2f(pv[j]) * scale[j] + shift[j]));
#pragma unroll
      for (int j = 0; j < 8; ++j)
        outv[8 + j] = f2bf(siluf(bf2f(pv1[j]) * scale[8 + j] + shift[8 + j]));
#pragma unroll
      for (int qq = 0; qq < 4; ++qq) {
        int ph = (qq + swz) & 3;
        *(uint2*)(dst + ph * 4) = *(const uint2*)(outv + qq * 4);
      }
    } else {
      *(uint4*)dst = make_uint4(0u, 0u, 0u, 0u);
      *(uint4*)(dst + 8) = make_uint4(0u, 0u, 0u, 0u);
    }
  }
  __syncthreads();

  int w = t & 63, q = t >> 6;
  float wv[9][4];
#pragma unroll
  for (int j = 0; j < 4; ++j) {
    int hc = hc0 + q * 4 + j;
#pragma unroll
    for (int tap = 0; tap < 9; ++tap) wv[tap][j] = w_dw[hc * 9 + tap];
  }

  f32x4 win[3][3];
  float acc_s = 0.f, acc_ss = 0.f;

  auto ld4 = [&](int r, int dwi) -> f32x4 {
    int slot = w + dwi;
    int ph = (q + (slot >> 2)) & 3;
    const bf16* p = tile + (r * 66 + slot) * 16 + ph * 4;
    uint2 u = *(const uint2*)p;
    const bf16* pb = (const bf16*)&u;
    return (f32x4){bf2f(pb[0]), bf2f(pb[1]), bf2f(pb[2]), bf2f(pb[3])};
  };

#pragma unroll
  for (int dwi = 0; dwi < 3; ++dwi) {
    win[0][dwi] = ld4(0, dwi);
    win[1][dwi] = ld4(1, dwi);
  }
#pragma unroll
  for (int orow = 0; orow < 16; ++orow) {
    int rnew = orow + 2;
    int ringn = rnew % 3;
#pragma unroll
    for (int dwi = 0; dwi < 3; ++dwi) win[ringn][dwi] = ld4(rnew, dwi);
    f32x4 acc = (f32x4){0.f, 0.f, 0.f, 0.f};
#pragma unroll
    for (int dr = 0; dr < 3; ++dr) {
      int ring = (orow + dr) % 3;
#pragma unroll
      for (int dwi = 0; dwi < 3; ++dwi) {
#pragma unroll
        for (int j = 0; j < 4; ++j)
          acc[j] = fmaf(win[ring][dwi][j], wv[dr * 3 + dwi][j], acc[j]);
      }
    }
#pragma unroll
    for (int j = 0; j < 4; ++j) { acc_s += acc[j]; acc_ss += acc[j] * acc[j]; }
    if (!(orow & 1) && !(w & 1)) {
      int hglob = h0 + orow;
      int pos2 = (hglob >> 1) * 32 + (w >> 1);
      bf16 tmp[4];
#pragma unroll
      for (int j = 0; j < 4; ++j) tmp[j] = f2bf(acc[j]);
      *(uint2*)((char*)h2cl + ((size_t)(b * 1024 + pos2) * 512 + hc0 + q * 4) * 2) =
          *(const uint2*)tmp;
    }
  }

#pragma unroll
  for (int off = 32; off; off >>= 1) {
    acc_s += __shfl_down(acc_s, off, 64);
    acc_ss += __shfl_down(acc_ss, off, 64);
  }
  int wave = t >> 6;
  if ((t & 63) == 0) { red2[wave][0] = acc_s; red2[wave][1] = acc_ss; }
  __syncthreads();
  if (t < 2) {
    float v = red2[0][t] + red2[1][t] + red2[2][t] + red2[3][t];
    atomicAdd(&stats2[(b * 8 + hcb) * 2 + t], v);
  }
}

// ---------------- pw2 MFMA (GN2+SiLU fused; grid 512, co-halved) -----------
__global__ __launch_bounds__(256) void pw2_mfma(
    const bf16* __restrict__ h2, const bf16* __restrict__ wp2T,
    const float* __restrict__ st2, const float* __restrict__ gs2,
    const float* __restrict__ gb2, float* __restrict__ h3,
    float* __restrict__ stats3) {
  __shared__ __align__(16) char als[2][4096];
  __shared__ __align__(16) char bls[2][4096];
  __shared__ float red[4][4][2];
  int blk = blockIdx.x;
  int mhalf = blk >> 8;
  int nblk = blk & 255;
  int n0 = nblk * 64;
  int m0 = mhalf * 64;
  int b = n0 >> 10, posb = n0 & 1023;
  int t = threadIdx.x, lane = t & 63, wave = t >> 6;
  int quad = lane >> 4, l15 = lane & 15;
  int wbase = wave * 16;
  int c4 = t >> 6, r = t & 63;

  auto load_bls = [&](char* dst, int kc) {
    int hc0 = (kc * 4 + c4) * 8;
    int g = hc0 >> 6;
    float S = st2[(b * 8 + g) * 2], SS = st2[(b * 8 + g) * 2 + 1];
    float mean = S * (1.f / 262144.f);
    float rstd = rsqrtf(SS * (1.f / 262144.f) - mean * mean + 1e-5f);
    uint4 u = *(const uint4*)((const char*)h2 + (size_t)(n0 + r) * 1024 +
                              (size_t)(kc * 4 + c4) * 16);
    const bf16* pv = (const bf16*)&u;
    bf16 outv[8];
#pragma unroll
    for (int j = 0; j < 8; ++j) {
      float xv = bf2f(pv[j]);
      xv = (xv - mean) * rstd * gs2[hc0 + j] + gb2[hc0 + j];
      outv[j] = f2bf(siluf(xv));
    }
    *(uint4*)dst = *(const uint4*)outv;
  };
  auto load_als = [&](char* dstbase, int kc) {
    *(uint4*)(dstbase + c4 * 1024 + r * 16) =
        *(const uint4*)((const char*)wp2T + (size_t)(m0 + r) * 1024 +
                        (size_t)(kc * 4 + c4) * 16);
  };

  f32x4 acc[4];
#pragma unroll
  for (int mt = 0; mt < 4; ++mt) acc[mt] = (f32x4){0.f, 0.f, 0.f, 0.f};

  {
    load_als(als[0], 0);
    load_bls(bls[0] + c4 * 1024 + r * 16, 0);
  }
#pragma unroll
  for (int kc = 0; kc < 16; ++kc) {
    __syncthreads();
    if (kc + 1 < 16) {
      int nb = (kc + 1) & 1;
      load_als(als[nb], kc + 1);
      load_bls(bls[nb] + c4 * 1024 + r * 16, kc + 1);
    }
    int buf = kc & 1;
    bf16x8 bf1 = *(const bf16x8*)(bls[buf] + quad * 1024 + (wbase + l15) * 16);
#pragma unroll
    for (int mt = 0; mt < 4; ++mt) {
      bf16x8 af = *(const bf16x8*)(als[buf] + quad * 1024 + (mt * 16 + l15) * 16);
      acc[mt] = __builtin_amdgcn_mfma_f32_16x16x32_bf16(af, bf1, acc[mt], 0, 0, 0);
    }
  }

#pragma unroll
  for (int mt = 0; mt < 4; ++mt) {
    float s = 0.f, ss = 0.f;
    int pos = posb + wbase + l15;
#pragma unroll
    for (int rr = 0; rr < 4; ++rr) {
      float v = acc[mt][rr];
      s += v;
      ss += v * v;
      int co = m0 + mt * 16 + quad * 4 + rr;
      h3[(size_t)(b * 128 + co) * 1024 + pos] = v;
    }
#pragma unroll
    for (int off = 32; off; off >>= 1) {
      s += __shfl_down(s, off, 64);
      ss += __shfl_down(ss, off, 64);
    }
    if (lane == 0) { red[wave][mt][0] = s; red[wave][mt][1] = ss; }
  }
  __syncthreads();
  if (t < 8) {
    int mt = t >> 1, which = t & 1;
    float v = red[0][mt][which] + red[1][mt][which] + red[2][mt][which] + red[3][mt][which];
    atomicAdd(&stats3[(b * 8 + mhalf * 4 + mt) * 2 + which], v);
  }
}

// ---------------- final GN+SiLU -> d_out (fp32, float4) --------------------
__global__ void out_kernel(const float* __restrict__ h3, const float* __restrict__ stats,
                           const float* __restrict__ gs, const float* __restrict__ gb,
                           float* __restrict__ out) {
  const int total4 = (B_ * COUT_ * 1024) >> 2;
  for (int i4 = blockIdx.x * blockDim.x + threadIdx.x; i4 < total4;
       i4 += gridDim.x * blockDim.x) {
    int idx = i4 << 2;
    int c = (idx >> 10) & 127;
    int b = idx >> 17;
    int bg = b * 8 + (c >> 4);
    float S = stats[bg * 2], SS = stats[bg * 2 + 1];
    float mean = S * (1.f / 16384.f);
    float var = SS * (1.f / 16384.f) - mean * mean;
    float rstd = rsqrtf(var + 1e-5f);
    float sc = rstd * gs[c];
    float sh = gb[c] - mean * sc;
    float4 hv = *(const float4*)(h3 + idx);
    float4 res;
    res.x = siluf(hv.x * sc + sh);
    res.y = siluf(hv.y * sc + sh);
    res.z = siluf(hv.z * sc + sh);
    res.w = siluf(hv.w * sc + sh);
    *(float4*)(out + idx) = res;
  }
}

extern "C" void kernel_launch(void* const* d_in, const int* in_sizes, int n_in,
                              void* d_out, int out_size, void* d_ws, size_t ws_size,
                              hipStream_t stream) {
  const float* x = (const float*)d_in[0];
  const float* w_exp = (const float*)d_in[1];
  const float* gn_exp_s = (const float*)d_in[2];
  const float* gn_exp_b = (const float*)d_in[3];
  const float* w1 = (const float*)d_in[4];
  const float* b1 = (const float*)d_in[5];
  const float* w2 = (const float*)d_in[6];
  const float* b2 = (const float*)d_in[7];
  const float* w_pw1 = (const float*)d_in[8];
  const float* gn1_s = (const float*)d_in[9];
  const float* gn1_b = (const float*)d_in[10];
  const float* w_dw = (const float*)d_in[11];
  const float* gn2_s = (const float*)d_in[12];
  const float* gn2_b = (const float*)d_in[13];
  const float* w_pw2 = (const float*)d_in[14];
  const float* gn3_s = (const float*)d_in[15];
  const float* gn3_b = (const float*)d_in[16];

  char* ws = (char*)d_ws;
  const size_t WP1T_OFF = 16384;
  const size_t WP2T_OFF = WP1T_OFF + 131072;
  const size_t XT_OFF = WP2T_OFF + 131072;                 // 278528
  const size_t WT_OFF = XT_OFF + 16777216;                 // 17055744
  const size_t YS_OFF = WT_OFF + 2359296;                  // 19415040
  const size_t NEEDED = YS_OFF + 134217728;                // 153632768
  const size_t H1_OFF = YS_OFF + 134217728;                // layout A
  const size_t NEEDED_BIG = H1_OFF + 67108864;             // 220741632
  if (ws_size < NEEDED) return;
  bool big = ws_size >= NEEDED_BIG;

  float* wts = (float*)ws;
  float* stats1 = (float*)(ws + 1024);
  float* stats2 = (float*)(ws + 2048);
  float* stats3 = (float*)(ws + 3072);
  float* statsE = (float*)(ws + 4096);
  bf16* wp1T = (bf16*)(ws + WP1T_OFF);
  bf16* wp2T = (bf16*)(ws + WP2T_OFF);
  bf16* xT = (bf16*)(ws + XT_OFF);
  bf16* wT = (bf16*)(ws + WT_OFF);
  bf16* ys = (bf16*)(ws + YS_OFF);

  prep_kernel<<<6145, 256, 0, stream>>>(x, xT, w_exp, wT, w_pw1, w_pw2, wp1T, wp2T,
                                        w1, b1, w2, b2, wts);
  conv_mfma<<<2048, 256, 0, stream>>>(xT, wT, statsE, ys);

  if (big) {
    // Layout A: h1cl disjoint from ys; h2cl/h3 recycle the dead ys region.
    bf16* h1cl = (bf16*)(ws + H1_OFF);
    bf16* h2cl = (bf16*)(ws + YS_OFF);
    float* h3 = (float*)(ws + YS_OFF + 16777216);
    combine_pw1<<<512, 256, 0, stream>>>(x, ys, statsE, gn_exp_s, gn_exp_b, wts,
                                         wp1T, h1cl, stats1);
    dw_cl<<<B_ * 32 * 4, 256, 0, stream>>>(h1cl, w_dw, stats1, gn1_s, gn1_b, h2cl, stats2);
    pw2_mfma<<<512, 256, 0, stream>>>(h2cl, wp2T, stats2, gn2_s, gn2_b, h3, stats3);
    out_kernel<<<1024, 256, 0, stream>>>(h3, stats3, gn3_s, gn3_b, (float*)d_out);
  } else {
    // Layout B (R15-verified): ccl in dead xT region; h1cl aliases ys (legal:
    // pw1 reads ccl, not ys).
    bf16* ccl = (bf16*)(ws + XT_OFF);
    bf16* h1cl = (bf16*)(ws + YS_OFF);
    bf16* h2cl = (bf16*)(ws + YS_OFF + 67108864);
    float* h3 = (float*)(ws + YS_OFF + 83886080);
    combine_cl<<<B_ * 64, 256, 0, stream>>>(x, ys, statsE, gn_exp_s, gn_exp_b, wts, ccl);
    pw1_mfma<<<512, 256, 0, stream>>>(ccl, wp1T, h1cl, stats1);
    dw_cl<<<B_ * 32 * 4, 256, 0, stream>>>(h1cl, w_dw, stats1, gn1_s, gn1_b, h2cl, stats2);
    pw2_mfma<<<512, 256, 0, stream>>>(h2cl, wp2T, stats2, gn2_s, gn2_b, h3, stats3);
    out_kernel<<<1024, 256, 0, stream>>>(h3, stats3, gn3_s, gn3_b, (float*)d_out);
  }
}

// Round 13
// 443.328 us; speedup vs baseline: 1.0181x; 1.0181x over previous
//
#include <hip/hip_runtime.h>
#include <hip/hip_bf16.h>

// ---------------------------------------------------------------------------
// PCELayer R18 = R15 structure exactly (best-known 432.9us; the R16/R17
// combine+pw1 fusion LOST ~18us and is deleted), with conv_mfma split into
// FOUR dispatches (e_base 0/2/4/6, 512 blocks each, ~39us) so the largest
// non-conv kernels surface in the rocprof top-5 WITH their counters
// (hbm_gbps / VALUBusy / MfmaUtil / Occupancy). The ~275us non-conv stack
// runs at ~1.6TB/s effective and has resisted 4 blind structural rounds;
// this purchases the measurement needed to diagnose it.
// Components: prep merged | conv R10-pareto | combine_cl octet-vec XCD-swz |
// pw1 B-once mtile-loop | dw staged stencil | pw2 GN2-fused grid-512 |
// out float4. rcp-SiLU everywhere. Stats finalize inlined. No memset.
// Workspace (153.6 MB): head 16K | wp1T 128K | wp2T 128K | XT 16.8M (->ccl)
//   | WT 2.4M | YS 134.2M (-> h1cl 67M | h2cl 16.8M | h3 8.4M)
// ---------------------------------------------------------------------------

#define B_ 16
#define CIN_ 128
#define COUT_ 128
#define H_ 64
#define W_ 64
#define HW_ 4096
#define E_ 8
#define FF_ 8
#define GC_ 32
#define HID_ 64
#define HC_ 512

typedef __hip_bfloat16 bf16;
typedef __bf16 bf16x8 __attribute__((ext_vector_type(8)));
typedef float f32x4 __attribute__((ext_vector_type(4)));
typedef float f32x16 __attribute__((ext_vector_type(16)));

__device__ __forceinline__ float siluf(float v) {
  return v * __builtin_amdgcn_rcpf(1.f + __expf(-v));
}
__device__ __forceinline__ float bf2f(bf16 v) { return __bfloat162float(v); }
__device__ __forceinline__ bf16 f2bf(float v) { return __float2bfloat16(v); }

__device__ __forceinline__ void async16(void* lds, const void* g) {
  __builtin_amdgcn_global_load_lds(
      (const __attribute__((address_space(1))) unsigned int*)g,
      (__attribute__((address_space(3))) unsigned int*)lds, 16, 0, 0);
}

// ---------------- merged prep: xt | wt | wpT | gate+statszero ---------------
__global__ __launch_bounds__(256) void prep_kernel(
    const float* __restrict__ x, bf16* __restrict__ xT,
    const float* __restrict__ w_exp, bf16* __restrict__ wT,
    const float* __restrict__ w_pw1, const float* __restrict__ w_pw2,
    bf16* __restrict__ wp1T, bf16* __restrict__ wp2T,
    const float* __restrict__ w1, const float* __restrict__ b1,
    const float* __restrict__ w2, const float* __restrict__ b2,
    float* __restrict__ wts) {
  __shared__ float t[128][65];
  int blk = blockIdx.x;
  int tid = threadIdx.x;

  if (blk < 1024) {
    int b = blk >> 6, h = blk & 63;
    int w = tid & 63, c4 = tid >> 6;
    const float* xb = x + ((size_t)(b * 128) * 64 + h) * 64;
#pragma unroll 4
    for (int rep = 0; rep < 32; ++rep) {
      int ci = rep * 4 + c4;
      t[ci][w] = xb[(size_t)ci * HW_ + w];
    }
    __syncthreads();
    bf16* dst = xT + (size_t)(b * 64 + h) * 8192;
#pragma unroll 4
    for (int rep = 0; rep < 32; ++rep) {
      int o = rep * 256 + tid;
      int cg = o >> 9, w2 = (o >> 3) & 63, lo = o & 7;
      dst[o] = f2bf(t[cg * 8 + lo][w2]);
    }
  } else if (blk < 5632) {
    int idx = (blk - 1024) * 256 + tid;
    if (idx < 1179648) {
      int lo = idx & 7;
      int co = (idx >> 3) & 127;
      int cg = (idx >> 10) & 15;
      int rest = idx >> 14;
      int tap = rest % 9, e = rest / 9;
      int ci = cg * 8 + lo;
      wT[idx] = f2bf(w_exp[(((size_t)(e * 128 + co) * 128 + ci) * 9) + tap]);
    }
  } else if (blk < 6144) {
    int idx = (blk - 5632) * 256 + tid;
    if (idx < 65536) wp1T[idx] = f2bf(w_pw1[idx]);
    else wp2T[idx - 65536] = f2bf(w_pw2[idx - 65536]);
  } else {
    uint4* z = (uint4*)((char*)wts + 1024);
    for (int i = tid; i < 960; i += 256) z[i] = make_uint4(0u, 0u, 0u, 0u);
    int p = tid;
    if (p >= 16) return;
    int i = p >> 2, j = p & 3;
    float cy = (i + 0.5f) * 0.25f;
    float cx = (j + 0.5f) * 0.25f;
    float feats[GC_];
#pragma unroll
    for (int f = 0; f < FF_; ++f) {
      float fr = 3.14159265358979f * (float)(1 << f);
      float ay = cy * fr, ax = cx * fr;
      feats[f] = sinf(ay);
      feats[FF_ + f] = cosf(ay);
      feats[2 * FF_ + f] = sinf(ax);
      feats[3 * FF_ + f] = cosf(ax);
    }
    float hid[HID_];
    for (int k = 0; k < HID_; ++k) {
      float a = b1[k];
#pragma unroll
      for (int m = 0; m < GC_; ++m) a = fmaf(feats[m], w1[m * HID_ + k], a);
      hid[k] = siluf(a);
    }
    float lg[E_];
    float mx = -1e30f;
#pragma unroll
    for (int e = 0; e < E_; ++e) {
      float a = b2[e];
      for (int k = 0; k < HID_; ++k) a = fmaf(hid[k], w2[k * E_ + e], a);
      lg[e] = a;
      mx = fmaxf(mx, a);
    }
    float s = 0.f;
#pragma unroll
    for (int e = 0; e < E_; ++e) { lg[e] = __expf(lg[e] - mx); s += lg[e]; }
    float inv = 1.f / s;
#pragma unroll
    for (int e = 0; e < E_; ++e) wts[p * E_ + e] = lg[e] * inv;
  }
}

// ---------------- expert conv via MFMA (R10 v7, 4-way split on e_base) -----
// grid 512 per dispatch: covers experts e_base..e_base+1.
__global__ __launch_bounds__(256, 2) void conv_mfma(
    const bf16* __restrict__ xT, const bf16* __restrict__ wT,
    float* __restrict__ statsE, bf16* __restrict__ ys, int e_base) {
  __shared__ __align__(16) char xls[4 * 6336];
  __shared__ __align__(16) char wls[2][3 * 8192];
  __shared__ float red[4][8][2];

  int blk = blockIdx.x;
  int xcd = blk & 7;
  int r2 = blk >> 3;                  // 0..63
  int b = xcd * 2 + (r2 & 1);
  int rest = r2 >> 1;                 // 0..31
  int rt = rest & 15, e = e_base + (rest >> 4);

  int tid = threadIdx.x, lane = tid & 63, wave = tid >> 6;
  int hi = lane >> 5, l31 = lane & 31;
  int h0 = rt * 4;

  if (tid < 48) {
    int cg = tid / 12, rem = tid % 12;
    int r = rem >> 1, edge = rem & 1;
    *(uint4*)(xls + cg * 6336 + r * 1056 + edge * 1040) = make_uint4(0u, 0u, 0u, 0u);
  }
  int rbad = (rt == 0) ? 0 : (rt == 15 ? 5 : -1);
  if (rbad >= 0) {
    int cg = tid >> 6, slot = (tid & 63) + 1;
    *(uint4*)(xls + cg * 6336 + rbad * 1056 + slot * 16) = make_uint4(0u, 0u, 0u, 0u);
  }

  f32x16 acc[4][2];
#pragma unroll
  for (int mt = 0; mt < 4; ++mt)
#pragma unroll
    for (int nt = 0; nt < 2; ++nt)
#pragma unroll
      for (int r = 0; r < 16; ++r) acc[mt][nt][r] = 0.f;

  for (int q = 0; q < 4; ++q) {
    if (q) __syncthreads();
    {
      int cg = wave;
#pragma unroll
      for (int r = 0; r < 6; ++r) {
        int h = h0 - 1 + r;
        if ((unsigned)h < 64u) {
          const char* g = (const char*)xT +
              ((size_t)((b * 64 + h) * 16) + q * 4 + cg) * 1024 + lane * 16;
          async16(xls + cg * 6336 + r * 1056 + 16, g);
        }
      }
    }
#pragma unroll
    for (int s = 0; s < 6; ++s) {
      int seg = wave * 6 + s;
      int tap = seg >> 3, rem = seg & 7;
      int cg = rem >> 1, cb = rem & 1;
      const char* g = (const char*)wT +
          ((size_t)(((e * 9 + tap) * 16) + q * 4 + cg) * 128 + cb * 64) * 16 + lane * 16;
      async16(wls[0] + (tap * 4 + cg) * 2048 + cb * 1024, g);
    }
    __syncthreads();

    for (int dr = 0; dr < 3; ++dr) {
      int buf = dr & 1;
      if (dr < 2) {
#pragma unroll
        for (int s = 0; s < 6; ++s) {
          int seg = wave * 6 + s;
          int tap = seg >> 3, rem = seg & 7;
          int cg = rem >> 1, cb = rem & 1;
          const char* g = (const char*)wT +
              ((size_t)(((e * 9 + (dr + 1) * 3 + tap) * 16) + q * 4 + cg) * 128 + cb * 64) * 16 +
              lane * 16;
          async16(wls[buf ^ 1] + (tap * 4 + cg) * 2048 + cb * 1024, g);
        }
      }
      int r_local = wave + dr;
      const char* wb = wls[buf];
      const char* xrow = xls;
      bf16x8 afp[2][2], bfp[2][2];
      {
        int cgl = hi;
        afp[0][0] = *(const bf16x8*)(wb + cgl * 2048 + (0 * 32 + l31) * 16);
        afp[0][1] = *(const bf16x8*)(wb + cgl * 2048 + (1 * 32 + l31) * 16);
        const char* xr = xrow + cgl * 6336 + r_local * 1056;
        bfp[0][0] = *(const bf16x8*)(xr + (0 * 32 + l31 + 0) * 16);
        bfp[0][1] = *(const bf16x8*)(xr + (1 * 32 + l31 + 0) * 16);
      }
#pragma unroll
      for (int s = 0; s < 12; ++s) {
        int mh = s & 1;
        int cura = s & 1, curb = (s >> 1) & 1;
        if (s < 11) {
          int s1 = s + 1;
          int ds1 = s1 >> 2, ks1 = (s1 >> 1) & 1, mh1 = s1 & 1;
          int cgl1 = ks1 * 2 + hi;
          const char* wt1 = wb + ds1 * 8192 + cgl1 * 2048;
          afp[s1 & 1][0] = *(const bf16x8*)(wt1 + ((mh1 * 2 + 0) * 32 + l31) * 16);
          afp[s1 & 1][1] = *(const bf16x8*)(wt1 + ((mh1 * 2 + 1) * 32 + l31) * 16);
          if (mh1 == 0) {
            const char* xr1 = xrow + cgl1 * 6336 + r_local * 1056;
            bfp[(s1 >> 1) & 1][0] = *(const bf16x8*)(xr1 + (0 * 32 + l31 + ds1) * 16);
            bfp[(s1 >> 1) & 1][1] = *(const bf16x8*)(xr1 + (1 * 32 + l31 + ds1) * 16);
          }
        }
#pragma unroll
        for (int i = 0; i < 2; ++i)
#pragma unroll
          for (int nt = 0; nt < 2; ++nt)
            acc[mh * 2 + i][nt] = __builtin_amdgcn_mfma_f32_32x32x16_bf16(
                afp[cura][i], bfp[curb][nt], acc[mh * 2 + i][nt], 0, 0, 0);
      }
      if (dr < 2) __syncthreads();
    }
  }

  int hh = h0 + wave;
  bf16* yb = ys + (size_t)((e * 16 + b) * 128) * 4096;
#pragma unroll
  for (int mt = 0; mt < 4; ++mt) {
    float s0 = 0.f, ss0 = 0.f, s1 = 0.f, ss1 = 0.f;
#pragma unroll
    for (int nt = 0; nt < 2; ++nt) {
      int w = nt * 32 + l31;
      int pos = hh * 64 + w;
#pragma unroll
      for (int r = 0; r < 16; ++r) {
        float v = acc[mt][nt][r];
        if (r < 8) { s0 += v; ss0 += v * v; } else { s1 += v; ss1 += v * v; }
        int row = (r & 3) + 8 * (r >> 2) + 4 * hi;
        yb[(size_t)(mt * 32 + row) * 4096 + pos] = f2bf(v);
      }
    }
#pragma unroll
    for (int off = 32; off; off >>= 1) {
      s0 += __shfl_down(s0, off, 64);
      ss0 += __shfl_down(ss0, off, 64);
      s1 += __shfl_down(s1, off, 64);
      ss1 += __shfl_down(ss1, off, 64);
    }
    if (lane == 0) {
      red[wave][mt * 2][0] = s0; red[wave][mt * 2][1] = ss0;
      red[wave][mt * 2 + 1][0] = s1; red[wave][mt * 2 + 1][1] = ss1;
    }
  }
  __syncthreads();
  if (tid < 16) {
    int g = tid >> 1, which = tid & 1;
    float t = red[0][g][which] + red[1][g][which] + red[2][g][which] + red[3][g][which];
    atomicAdd(&statsE[((e * 16 + b) * 8 + g) * 2 + which], t);
  }
}

// ---------------- combine -> bf16 channels-last (octet-vec, XCD-swizzled) --
__global__ __launch_bounds__(256) void combine_cl(
    const float* __restrict__ x, const bf16* __restrict__ ys,
    const float* __restrict__ stE, const float* __restrict__ gns,
    const float* __restrict__ gnb, const float* __restrict__ wts,
    bf16* __restrict__ ccl) {
  __shared__ bf16 tile[64][132];
  int blk = blockIdx.x;
  int xcd = blk & 7;
  int k2 = blk >> 3;
  int b = xcd * 2 + (k2 >> 6);
  int h = k2 & 63;
  int t = threadIdx.x;
  int oct = t & 7, cq = t >> 3;
  int w0 = oct * 8;
  int gidx = cq >> 2;
  int pid = (h >> 4) * 4 + (w0 >> 4);
  int pos = h * 64 + w0;

  float m_[8], r_[8], wt_[8];
#pragma unroll
  for (int e = 0; e < 8; ++e) {
    float S = stE[((e * 16 + b) * 8 + gidx) * 2];
    float SS = stE[((e * 16 + b) * 8 + gidx) * 2 + 1];
    float mean = S * (1.f / 65536.f);
    float var = SS * (1.f / 65536.f) - mean * mean;
    m_[e] = mean;
    r_[e] = rsqrtf(var + 1e-5f);
    wt_[e] = wts[pid * 8 + e];
  }

#pragma unroll
  for (int k = 0; k < 4; ++k) {
    int co = cq * 4 + k;
    const float* xp = x + ((size_t)(b * 128 + co) << 12) + pos;
    float v[8];
    float4 xa = *(const float4*)xp;
    float4 xb2 = *(const float4*)(xp + 4);
    v[0] = xa.x; v[1] = xa.y; v[2] = xa.z; v[3] = xa.w;
    v[4] = xb2.x; v[5] = xb2.y; v[6] = xb2.z; v[7] = xb2.w;
#pragma unroll
    for (int e = 0; e < 8; ++e) {
      uint4 u = *(const uint4*)(ys + ((size_t)((e * 16 + b) * 128 + co) << 12) + pos);
      const bf16* pv = (const bf16*)&u;
      float sc = r_[e] * gns[e * 128 + co];
      float sh = gnb[e * 128 + co] - m_[e] * sc;
#pragma unroll
      for (int j = 0; j < 8; ++j) {
        float yn = bf2f(pv[j]) * sc + sh;
        v[j] = fmaf(siluf(yn), wt_[e], v[j]);
      }
    }
#pragma unroll
    for (int j = 0; j < 8; ++j) tile[w0 + j][co] = f2bf(v[j]);
  }
  __syncthreads();
  int row = t >> 2, q = t & 3;
  char* dst = (char*)ccl + ((size_t)(b * 4096 + h * 64 + row)) * 256 + q * 64;
  const char* src = (const char*)&tile[row][0] + q * 64;
#pragma unroll
  for (int i = 0; i < 4; ++i)
    *(uint4*)(dst + i * 16) = *(const uint4*)(src + i * 16);
}

// ---------------- pw1 MFMA: B staged once, mtile loop ----------------------
__global__ __launch_bounds__(256) void pw1_mfma(
    const bf16* __restrict__ ccl, const bf16* __restrict__ wp1T,
    bf16* __restrict__ h1cl, float* __restrict__ stats1) {
  __shared__ __align__(16) char bls[32768];
  __shared__ __align__(16) char ls2[34816];
  __shared__ float red[4][2][2];
  int blk = blockIdx.x;
  int n0 = blk * 128;
  int t = threadIdx.x, lane = t & 63, wave = t >> 6;
  int quad = lane >> 4, l15 = lane & 15;
  int b = n0 >> 12;

#pragma unroll
  for (int i = 0; i < 8; ++i) {
    int id = t + 256 * i;
    int r = id >> 4, c = id & 15;
    *(uint4*)(bls + c * 2048 + r * 16) =
        *(const uint4*)((const char*)ccl + (size_t)(n0 + r) * 256 + c * 16);
  }

  for (int mtile = 0; mtile < 4; ++mtile) {
    int m0 = mtile * 128;
    char* als = ls2;
#pragma unroll
    for (int i = 0; i < 8; ++i) {
      int id = t + 256 * i;
      int r = id >> 4, c = id & 15;
      *(uint4*)(als + c * 2048 + r * 16) =
          *(const uint4*)((const char*)wp1T + (size_t)(m0 + r) * 256 + c * 16);
    }
    __syncthreads();

    f32x4 acc[8][2];
#pragma unroll
    for (int mt = 0; mt < 8; ++mt)
#pragma unroll
      for (int nt = 0; nt < 2; ++nt) acc[mt][nt] = (f32x4){0.f, 0.f, 0.f, 0.f};

#pragma unroll
    for (int kc = 0; kc < 4; ++kc) {
      int cgq = kc * 4 + quad;
      bf16x8 af[8];
#pragma unroll
      for (int mt = 0; mt < 8; ++mt)
        af[mt] = *(const bf16x8*)(als + cgq * 2048 + (mt * 16 + l15) * 16);
      bf16x8 bfr[2];
#pragma unroll
      for (int nt = 0; nt < 2; ++nt)
        bfr[nt] = *(const bf16x8*)(bls + cgq * 2048 + (wave * 32 + nt * 16 + l15) * 16);
#pragma unroll
      for (int mt = 0; mt < 8; ++mt)
#pragma unroll
        for (int nt = 0; nt < 2; ++nt)
          acc[mt][nt] = __builtin_amdgcn_mfma_f32_16x16x32_bf16(
              af[mt], bfr[nt], acc[mt][nt], 0, 0, 0);
    }

    __syncthreads();
    float s[2] = {0.f, 0.f}, ss[2] = {0.f, 0.f};
    bf16* tile = (bf16*)ls2;
#pragma unroll
    for (int mt = 0; mt < 8; ++mt) {
      int gi = mt >> 2;
#pragma unroll
      for (int nt = 0; nt < 2; ++nt) {
        int n = wave * 32 + nt * 16 + l15;
#pragma unroll
        for (int r = 0; r < 4; ++r) {
          float v = acc[mt][nt][r];
          s[gi] += v;
          ss[gi] += v * v;
          tile[n * 132 + mt * 16 + quad * 4 + r] = f2bf(v);
        }
      }
    }
#pragma unroll
    for (int gi = 0; gi < 2; ++gi) {
#pragma unroll
      for (int off = 32; off; off >>= 1) {
        s[gi] += __shfl_down(s[gi], off, 64);
        ss[gi] += __shfl_down(ss[gi], off, 64);
      }
    }
    if (lane == 0) {
      red[wave][0][0] = s[0]; red[wave][0][1] = ss[0];
      red[wave][1][0] = s[1]; red[wave][1][1] = ss[1];
    }
    __syncthreads();
    if (t < 4) {
      int gi = t >> 1, which = t & 1;
      float v = red[0][gi][which] + red[1][gi][which] + red[2][gi][which] + red[3][gi][which];
      atomicAdd(&stats1[(b * 8 + mtile * 2 + gi) * 2 + which], v);
    }
#pragma unroll
    for (int i = 0; i < 8; ++i) {
      int id = t + 256 * i;
      int r = id >> 4, q = id & 15;
      char* dst = (char*)h1cl + (size_t)(n0 + r) * 1024 + m0 * 2 + q * 16;
      const char* src = (const char*)tile + r * 264 + q * 16;
      *(uint4*)dst = *(const uint4*)src;
    }
    __syncthreads();
  }
}

// ---------------- dw3x3: LDS-staged GN1+SiLU tile + sliding stencil --------
__global__ __launch_bounds__(256) void dw_cl(
    const bf16* __restrict__ h1cl, const float* __restrict__ w_dw,
    const float* __restrict__ st1, const float* __restrict__ gs,
    const float* __restrict__ gb, bf16* __restrict__ h2cl,
    float* __restrict__ stats2) {
  __shared__ __align__(16) bf16 tile[18 * 66 * 16];
  __shared__ float red2[4][2];
  int blk = blockIdx.x;
  int ht = blk & 3, hcg = (blk >> 2) & 31, b = blk >> 7;
  int h0 = ht * 16;
  int hc0 = hcg * 16;
  int hcb = hcg >> 2;
  int t = threadIdx.x;

  float S1 = st1[(b * 8 + hcb) * 2], SS1 = st1[(b * 8 + hcb) * 2 + 1];
  float mean = S1 * (1.f / 262144.f);
  float var1 = SS1 * (1.f / 262144.f) - mean * mean;
  float rstd = rsqrtf(var1 + 1e-5f);
  float scale[16], shift[16];
#pragma unroll
  for (int j = 0; j < 16; ++j) {
    float g = gs[hc0 + j];
    scale[j] = rstd * g;
    shift[j] = gb[hc0 + j] - mean * rstd * g;
  }

  for (int i = 0; i < 5; ++i) {
    int idx = t + 256 * i;
    if (idx >= 1188) break;
    int row = idx / 66, wslot = idx - row * 66;
    int hh = h0 - 1 + row;
    int w = wslot - 1;
    int swz = (wslot >> 2) & 3;
    bf16* dst = tile + (row * 66 + wslot) * 16;
    if ((unsigned)hh < 64u && (unsigned)w < 64u) {
      const char* p = (const char*)h1cl + ((size_t)(b * 4096 + hh * 64 + w) * 512 + hc0) * 2;
      uint4 a0 = *(const uint4*)p;
      uint4 a1 = *(const uint4*)(p + 16);
      const bf16* pv = (const bf16*)&a0;
      const bf16* pv1 = (const bf16*)&a1;
      bf16 outv[16];
#pragma unroll
      for (int j = 0; j < 8; ++j)
        outv[j] = f2bf(siluf(bf2f(pv[j]) * scale[j] + shift[j]));
#pragma unroll
      for (int j = 0; j < 8; ++j)
        outv[8 + j] = f2bf(siluf(bf2f(pv1[j]) * scale[8 + j] + shift[8 + j]));
#pragma unroll
      for (int qq = 0; qq < 4; ++qq) {
        int ph = (qq + swz) & 3;
        *(uint2*)(dst + ph * 4) = *(const uint2*)(outv + qq * 4);
      }
    } else {
      *(uint4*)dst = make_uint4(0u, 0u, 0u, 0u);
      *(uint4*)(dst + 8) = make_uint4(0u, 0u, 0u, 0u);
    }
  }
  __syncthreads();

  int w = t & 63, q = t >> 6;
  float wv[9][4];
#pragma unroll
  for (int j = 0; j < 4; ++j) {
    int hc = hc0 + q * 4 + j;
#pragma unroll
    for (int tap = 0; tap < 9; ++tap) wv[tap][j] = w_dw[hc * 9 + tap];
  }

  f32x4 win[3][3];
  float acc_s = 0.f, acc_ss = 0.f;

  auto ld4 = [&](int r, int dwi) -> f32x4 {
    int slot = w + dwi;
    int ph = (q + (slot >> 2)) & 3;
    const bf16* p = tile + (r * 66 + slot) * 16 + ph * 4;
    uint2 u = *(const uint2*)p;
    const bf16* pb = (const bf16*)&u;
    return (f32x4){bf2f(pb[0]), bf2f(pb[1]), bf2f(pb[2]), bf2f(pb[3])};
  };

#pragma unroll
  for (int dwi = 0; dwi < 3; ++dwi) {
    win[0][dwi] = ld4(0, dwi);
    win[1][dwi] = ld4(1, dwi);
  }
#pragma unroll
  for (int orow = 0; orow < 16; ++orow) {
    int rnew = orow + 2;
    int ringn = rnew % 3;
#pragma unroll
    for (int dwi = 0; dwi < 3; ++dwi) win[ringn][dwi] = ld4(rnew, dwi);
    f32x4 acc = (f32x4){0.f, 0.f, 0.f, 0.f};
#pragma unroll
    for (int dr = 0; dr < 3; ++dr) {
      int ring = (orow + dr) % 3;
#pragma unroll
      for (int dwi = 0; dwi < 3; ++dwi) {
#pragma unroll
        for (int j = 0; j < 4; ++j)
          acc[j] = fmaf(win[ring][dwi][j], wv[dr * 3 + dwi][j], acc[j]);
      }
    }
#pragma unroll
    for (int j = 0; j < 4; ++j) { acc_s += acc[j]; acc_ss += acc[j] * acc[j]; }
    if (!(orow & 1) && !(w & 1)) {
      int hglob = h0 + orow;
      int pos2 = (hglob >> 1) * 32 + (w >> 1);
      bf16 tmp[4];
#pragma unroll
      for (int j = 0; j < 4; ++j) tmp[j] = f2bf(acc[j]);
      *(uint2*)((char*)h2cl + ((size_t)(b * 1024 + pos2) * 512 + hc0 + q * 4) * 2) =
          *(const uint2*)tmp;
    }
  }

#pragma unroll
  for (int off = 32; off; off >>= 1) {
    acc_s += __shfl_down(acc_s, off, 64);
    acc_ss += __shfl_down(acc_ss, off, 64);
  }
  int wave = t >> 6;
  if ((t & 63) == 0) { red2[wave][0] = acc_s; red2[wave][1] = acc_ss; }
  __syncthreads();
  if (t < 2) {
    float v = red2[0][t] + red2[1][t] + red2[2][t] + red2[3][t];
    atomicAdd(&stats2[(b * 8 + hcb) * 2 + t], v);
  }
}

// ---------------- pw2 MFMA (GN2+SiLU fused; grid 512, co-halved) -----------
__global__ __launch_bounds__(256) void pw2_mfma(
    const bf16* __restrict__ h2, const bf16* __restrict__ wp2T,
    const float* __restrict__ st2, const float* __restrict__ gs2,
    const float* __restrict__ gb2, float* __restrict__ h3,
    float* __restrict__ stats3) {
  __shared__ __align__(16) char als[2][4096];
  __shared__ __align__(16) char bls[2][4096];
  __shared__ float red[4][4][2];
  int blk = blockIdx.x;
  int mhalf = blk >> 8;
  int nblk = blk & 255;
  int n0 = nblk * 64;
  int m0 = mhalf * 64;
  int b = n0 >> 10, posb = n0 & 1023;
  int t = threadIdx.x, lane = t & 63, wave = t >> 6;
  int quad = lane >> 4, l15 = lane & 15;
  int wbase = wave * 16;
  int c4 = t >> 6, r = t & 63;

  auto load_bls = [&](char* dst, int kc) {
    int hc0 = (kc * 4 + c4) * 8;
    int g = hc0 >> 6;
    float S = st2[(b * 8 + g) * 2], SS = st2[(b * 8 + g) * 2 + 1];
    float mean = S * (1.f / 262144.f);
    float rstd = rsqrtf(SS * (1.f / 262144.f) - mean * mean + 1e-5f);
    uint4 u = *(const uint4*)((const char*)h2 + (size_t)(n0 + r) * 1024 +
                              (size_t)(kc * 4 + c4) * 16);
    const bf16* pv = (const bf16*)&u;
    bf16 outv[8];
#pragma unroll
    for (int j = 0; j < 8; ++j) {
      float xv = bf2f(pv[j]);
      xv = (xv - mean) * rstd * gs2[hc0 + j] + gb2[hc0 + j];
      outv[j] = f2bf(siluf(xv));
    }
    *(uint4*)dst = *(const uint4*)outv;
  };
  auto load_als = [&](char* dstbase, int kc) {
    *(uint4*)(dstbase + c4 * 1024 + r * 16) =
        *(const uint4*)((const char*)wp2T + (size_t)(m0 + r) * 1024 +
                        (size_t)(kc * 4 + c4) * 16);
  };

  f32x4 acc[4];
#pragma unroll
  for (int mt = 0; mt < 4; ++mt) acc[mt] = (f32x4){0.f, 0.f, 0.f, 0.f};

  {
    load_als(als[0], 0);
    load_bls(bls[0] + c4 * 1024 + r * 16, 0);
  }
#pragma unroll
  for (int kc = 0; kc < 16; ++kc) {
    __syncthreads();
    if (kc + 1 < 16) {
      int nb = (kc + 1) & 1;
      load_als(als[nb], kc + 1);
      load_bls(bls[nb] + c4 * 1024 + r * 16, kc + 1);
    }
    int buf = kc & 1;
    bf16x8 bf1 = *(const bf16x8*)(bls[buf] + quad * 1024 + (wbase + l15) * 16);
#pragma unroll
    for (int mt = 0; mt < 4; ++mt) {
      bf16x8 af = *(const bf16x8*)(als[buf] + quad * 1024 + (mt * 16 + l15) * 16);
      acc[mt] = __builtin_amdgcn_mfma_f32_16x16x32_bf16(af, bf1, acc[mt], 0, 0, 0);
    }
  }

#pragma unroll
  for (int mt = 0; mt < 4; ++mt) {
    float s = 0.f, ss = 0.f;
    int pos = posb + wbase + l15;
#pragma unroll
    for (int rr = 0; rr < 4; ++rr) {
      float v = acc[mt][rr];
      s += v;
      ss += v * v;
      int co = m0 + mt * 16 + quad * 4 + rr;
      h3[(size_t)(b * 128 + co) * 1024 + pos] = v;
    }
#pragma unroll
    for (int off = 32; off; off >>= 1) {
      s += __shfl_down(s, off, 64);
      ss += __shfl_down(ss, off, 64);
    }
    if (lane == 0) { red[wave][mt][0] = s; red[wave][mt][1] = ss; }
  }
  __syncthreads();
  if (t < 8) {
    int mt = t >> 1, which = t & 1;
    float v = red[0][mt][which] + red[1][mt][which] + red[2][mt][which] + red[3][mt][which];
    atomicAdd(&stats3[(b * 8 + mhalf * 4 + mt) * 2 + which], v);
  }
}

// ---------------- final GN+SiLU -> d_out (fp32, float4) --------------------
__global__ void out_kernel(const float* __restrict__ h3, const float* __restrict__ stats,
                           const float* __restrict__ gs, const float* __restrict__ gb,
                           float* __restrict__ out) {
  const int total4 = (B_ * COUT_ * 1024) >> 2;
  for (int i4 = blockIdx.x * blockDim.x + threadIdx.x; i4 < total4;
       i4 += gridDim.x * blockDim.x) {
    int idx = i4 << 2;
    int c = (idx >> 10) & 127;
    int b = idx >> 17;
    int bg = b * 8 + (c >> 4);
    float S = stats[bg * 2], SS = stats[bg * 2 + 1];
    float mean = S * (1.f / 16384.f);
    float var = SS * (1.f / 16384.f) - mean * mean;
    float rstd = rsqrtf(var + 1e-5f);
    float sc = rstd * gs[c];
    float sh = gb[c] - mean * sc;
    float4 hv = *(const float4*)(h3 + idx);
    float4 res;
    res.x = siluf(hv.x * sc + sh);
    res.y = siluf(hv.y * sc + sh);
    res.z = siluf(hv.z * sc + sh);
    res.w = siluf(hv.w * sc + sh);
    *(float4*)(out + idx) = res;
  }
}

extern "C" void kernel_launch(void* const* d_in, const int* in_sizes, int n_in,
                              void* d_out, int out_size, void* d_ws, size_t ws_size,
                              hipStream_t stream) {
  const float* x = (const float*)d_in[0];
  const float* w_exp = (const float*)d_in[1];
  const float* gn_exp_s = (const float*)d_in[2];
  const float* gn_exp_b = (const float*)d_in[3];
  const float* w1 = (const float*)d_in[4];
  const float* b1 = (const float*)d_in[5];
  const float* w2 = (const float*)d_in[6];
  const float* b2 = (const float*)d_in[7];
  const float* w_pw1 = (const float*)d_in[8];
  const float* gn1_s = (const float*)d_in[9];
  const float* gn1_b = (const float*)d_in[10];
  const float* w_dw = (const float*)d_in[11];
  const float* gn2_s = (const float*)d_in[12];
  const float* gn2_b = (const float*)d_in[13];
  const float* w_pw2 = (const float*)d_in[14];
  const float* gn3_s = (const float*)d_in[15];
  const float* gn3_b = (const float*)d_in[16];

  char* ws = (char*)d_ws;
  const size_t WP1T_OFF = 16384;
  const size_t WP2T_OFF = WP1T_OFF + 131072;
  const size_t XT_OFF = WP2T_OFF + 131072;                 // 278528
  const size_t WT_OFF = XT_OFF + 16777216;                 // 17055744
  const size_t YS_OFF = WT_OFF + 2359296;                  // 19415040
  const size_t NEEDED = YS_OFF + 134217728;                // 153632768
  if (ws_size < NEEDED) return;

  float* wts = (float*)ws;
  float* stats1 = (float*)(ws + 1024);
  float* stats2 = (float*)(ws + 2048);
  float* stats3 = (float*)(ws + 3072);
  float* statsE = (float*)(ws + 4096);
  bf16* wp1T = (bf16*)(ws + WP1T_OFF);
  bf16* wp2T = (bf16*)(ws + WP2T_OFF);
  bf16* xT = (bf16*)(ws + XT_OFF);
  bf16* wT = (bf16*)(ws + WT_OFF);
  bf16* ys = (bf16*)(ws + YS_OFF);
  bf16* ccl = (bf16*)(ws + XT_OFF);
  bf16* h1cl = (bf16*)(ws + YS_OFF);
  bf16* h2cl = (bf16*)(ws + YS_OFF + 67108864);
  float* h3 = (float*)(ws + YS_OFF + 83886080);

  prep_kernel<<<6145, 256, 0, stream>>>(x, xT, w_exp, wT, w_pw1, w_pw2, wp1T, wp2T,
                                        w1, b1, w2, b2, wts);
  conv_mfma<<<512, 256, 0, stream>>>(xT, wT, statsE, ys, 0);
  conv_mfma<<<512, 256, 0, stream>>>(xT, wT, statsE, ys, 2);
  conv_mfma<<<512, 256, 0, stream>>>(xT, wT, statsE, ys, 4);
  conv_mfma<<<512, 256, 0, stream>>>(xT, wT, statsE, ys, 6);
  combine_cl<<<B_ * 64, 256, 0, stream>>>(x, ys, statsE, gn_exp_s, gn_exp_b, wts, ccl);
  pw1_mfma<<<512, 256, 0, stream>>>(ccl, wp1T, h1cl, stats1);
  dw_cl<<<B_ * 32 * 4, 256, 0, stream>>>(h1cl, w_dw, stats1, gn1_s, gn1_b, h2cl, stats2);
  pw2_mfma<<<512, 256, 0, stream>>>(h2cl, wp2T, stats2, gn2_s, gn2_b, h3, stats3);
  out_kernel<<<1024, 256, 0, stream>>>(h3, stats3, gn3_s, gn3_b, (float*)d_out);
}